// Round 6
// baseline (5381.277 us; speedup 1.0000x reference)
//
#include <hip/hip_runtime.h>
#include <hip/hip_bf16.h>

typedef __hip_bfloat16 bf16;
typedef float fx2 __attribute__((ext_vector_type(2)));

#define NL 4096      // L leaves
#define NH 128       // H hidden
#define NE 256       // E embed
#define NT 64        // T tags
#define NNODE 8191   // N = 2L-1
#define NDEPTH 12    // D = log2(L)
#define CH 16        // LSTM steps per chunk
#define NCHUNK (NL / CH)

// converted f32 weights, offsets into wf[] (floats)
#define OF_WIH   0
#define OF_WHH   131072
#define OF_BIH   196608
#define OF_BHH   197120
#define OF_WP2H  197632
#define OF_BP2H  230400
#define OF_WUNI  230528
#define OF_BUNI  238720
#define OF_WEDGE 238784
#define OF_BEDGE 1287360
#define WF_TOTAL 1291456

__device__ __forceinline__ float b2f(bf16 x) { return __bfloat162float(x); }

// pair-swap (lanes 2k <-> 2k+1) via DPP quad_perm [1,0,3,2] — pure VALU
__device__ __forceinline__ float dpp_pair_add(float x) {
  int yi = __builtin_amdgcn_mov_dpp(__float_as_int(x), 0xB1, 0xF, 0xF, true);
  return x + __int_as_float(yi);
}

// ------------------------------------------------ dtype detection (f32 vs bf16 delivery)
// Also zeroes the lstm spinner 'done' flag (flag[8]) every call.
__global__ void detect_kernel(const void* __restrict__ wedge_raw, int* __restrict__ flag) {
  __shared__ int cnt_sh[256];
  const unsigned short* p = (const unsigned short*)wedge_raw;
  int c = 0;
  for (int i = threadIdx.x; i < 32768; i += 256) {
    float v = __uint_as_float(((unsigned)p[2 * i]) << 16);
    if (fabsf(v) > 4.f) c++;
  }
  cnt_sh[threadIdx.x] = c;
  __syncthreads();
  for (int s = 128; s > 0; s >>= 1) {
    if (threadIdx.x < s) cnt_sh[threadIdx.x] += cnt_sh[threadIdx.x + s];
    __syncthreads();
  }
  if (threadIdx.x == 0) {
    flag[0] = cnt_sh[0];   // >100 => inputs are f32
    flag[8] = 0;           // lstm done-flag
  }
}

// ------------------------------------------------ convert all weights -> f32 in ws
__global__ void convert_kernel(const void* s0, const void* s1, const void* s2, const void* s3,
                               const void* s4, const void* s5, const void* s6, const void* s7,
                               const void* s8, const void* s9,
                               const int* __restrict__ flag, float* __restrict__ wf) {
  int i = blockIdx.x * 256 + threadIdx.x;
  if (i >= WF_TOTAL) return;
  const void* src; int local;
  if      (i < OF_WHH)   { src = s0; local = i; }
  else if (i < OF_BIH)   { src = s1; local = i - OF_WHH; }
  else if (i < OF_BHH)   { src = s2; local = i - OF_BIH; }
  else if (i < OF_WP2H)  { src = s3; local = i - OF_BHH; }
  else if (i < OF_BP2H)  { src = s4; local = i - OF_WP2H; }
  else if (i < OF_WUNI)  { src = s5; local = i - OF_BP2H; }
  else if (i < OF_BUNI)  { src = s6; local = i - OF_WUNI; }
  else if (i < OF_WEDGE) { src = s7; local = i - OF_BUNI; }
  else if (i < OF_BEDGE) { src = s8; local = i - OF_WEDGE; }
  else                   { src = s9; local = i - OF_BEDGE; }
  bool isf32 = (*flag) > 100;
  wf[i] = isf32 ? ((const float*)src)[local] : b2f(((const bf16*)src)[local]);
}

// ------------------------------------------------ G1T = emb[tok]@W_ih^T + b_ih + b_hh
// TRANSPOSED store: G1T[t][j*4 + g] (gates of row j adjacent).
__global__ __launch_bounds__(512) void g1_kernel(const int* __restrict__ tokens,
                                                 const void* __restrict__ emb_raw,
                                                 const int* __restrict__ flag,
                                                 const float* __restrict__ wf,
                                                 float* __restrict__ G1T) {
  __shared__ __attribute__((aligned(16))) float xs[8 * NE];
  const bool isf32 = (*flag) > 100;
  const int t0 = blockIdx.x * 8;
  for (int q = threadIdx.x; q < 8 * NE; q += 512) {
    int tok = q >> 8, e = q & 255;
    size_t off = (size_t)tokens[t0 + tok] * NE + e;
    xs[q] = isf32 ? ((const float*)emb_raw)[off] : b2f(((const bf16*)emb_raw)[off]);
  }
  __syncthreads();
  const int r = threadIdx.x;
  const float bias = wf[OF_BIH + r] + wf[OF_BHH + r];
  float acc[8];
#pragma unroll
  for (int k = 0; k < 8; ++k) acc[k] = bias;
  const float4* W4 = (const float4*)(wf + OF_WIH + (size_t)r * NE);
#pragma unroll 8
  for (int j = 0; j < 64; ++j) {
    float4 wv = W4[j];
#pragma unroll
    for (int tok = 0; tok < 8; ++tok) {
      float4 xv = ((const float4*)(xs + tok * NE))[j];
      acc[tok] += wv.x * xv.x + wv.y * xv.y + wv.z * xv.z + wv.w * xv.w;
    }
  }
  const int jj = r & 127, gg = r >> 7;
#pragma unroll
  for (int tok = 0; tok < 8; ++tok)
    G1T[(size_t)(t0 + tok) * 512 + jj * 4 + gg] = acc[tok];
}

// ------------------------------------------------ sequential LSTM + clock-keeper spinners
// Block 0: R5's 256-thread pair-split LSTM (zero global ops in step body, chunked
// G1 prefetch, LDS-only step barrier). Blocks 1..256: one 64-lane wave each parks
// on the other CUs burning FMA until block 0 raises 'done' — holds SCLK at high
// DPM state instead of idle-clock (lstm alone = 0.05% chip utilization).
__global__ __launch_bounds__(256, 1) void lstm_kernel(const float* __restrict__ wf,
                                                      const float* __restrict__ G1T,
                                                      float* __restrict__ hidden,
                                                      int* __restrict__ done) {
  if (blockIdx.x != 0) {                      // ---- spinner block
    if (threadIdx.x >= 64) return;            // one wave per CU is enough for DPM
    float a0 = 1.0f + threadIdx.x, a1 = 1.1f, a2 = 1.2f, a3 = 1.3f,
          a4 = 1.4f, a5 = 1.5f, a6 = 1.6f, a7 = 1.7f;
    while (__hip_atomic_load(done, __ATOMIC_RELAXED, __HIP_MEMORY_SCOPE_AGENT) == 0) {
#pragma unroll
      for (int i = 0; i < 256; ++i) {         // ~2K FMA between polls
        a0 = __builtin_fmaf(a0, 0.99999988f, 1e-9f);
        a1 = __builtin_fmaf(a1, 0.99999988f, 1e-9f);
        a2 = __builtin_fmaf(a2, 0.99999988f, 1e-9f);
        a3 = __builtin_fmaf(a3, 0.99999988f, 1e-9f);
        a4 = __builtin_fmaf(a4, 0.99999988f, 1e-9f);
        a5 = __builtin_fmaf(a5, 0.99999988f, 1e-9f);
        a6 = __builtin_fmaf(a6, 0.99999988f, 1e-9f);
        a7 = __builtin_fmaf(a7, 0.99999988f, 1e-9f);
      }
      if (a0 + a1 + a2 + a3 + a4 + a5 + a6 + a7 == 123.456789f)
        ((volatile float*)hidden)[0] = a0;    // unreachable sink (keeps chains alive)
    }
    return;
  }
  // ---- block 0: the LSTM
  const int t = threadIdx.x;
  const int j = t >> 1;                       // 0..127
  const int khalf = t & 1;
  __shared__ __attribute__((aligned(16))) float h_sh[2][NH];        // 1 KB ping-pong
  __shared__ __attribute__((aligned(16))) float G1buf[CH * 512];    // 32 KB gate chunk
  __shared__ __attribute__((aligned(16))) float hstage[CH * NH];    // 8 KB leaf-h stage
  fx2 w[4][32];                               // 4 gate rows x 64 f32 (this k-half)
#pragma unroll
  for (int g = 0; g < 4; ++g) {
    const float4* Wr = (const float4*)(wf + OF_WHH + (size_t)(j + 128 * g) * NH + khalf * 64);
#pragma unroll
    for (int q = 0; q < 16; ++q) {
      float4 v = Wr[q];
      fx2 a, b; a.x = v.x; a.y = v.y; b.x = v.z; b.y = v.w;
      w[g][2 * q] = a; w[g][2 * q + 1] = b;
    }
  }
  float c = 0.f;
  float4 hreg0, hreg1;                        // boundary h flush registers
  if (khalf == 0) h_sh[0][j] = 0.f;
  {                                           // preload chunk 0 straight into LDS
#pragma unroll
    for (int i = 0; i < 8; ++i) {
      float4 v = *(const float4*)&G1T[(size_t)i * 1024 + t * 4];
      *(float4*)&G1buf[i * 1024 + t * 4] = v;   // lane-contiguous: conflict-free
    }
  }
  __syncthreads();                            // full drain once, pre-loop
  for (int ch = 0; ch < NCHUNK; ++ch) {
    // ---- issue next chunk's G1 loads + previous chunk's h store (16 steps of slack)
    float4 gpre[8];
    {
      const float* gsrc = G1T + (size_t)((ch + 1 < NCHUNK) ? ch + 1 : NCHUNK - 1) * (CH * 512);
#pragma unroll
      for (int i = 0; i < 8; ++i)
        gpre[i] = *(const float4*)&gsrc[i * 1024 + t * 4];
    }
    if (ch > 0) {
      float* dst = hidden + (size_t)(NL - 1 + (ch - 1) * CH) * NH;
      *(float4*)&dst[t * 4] = hreg0;
      *(float4*)&dst[1024 + t * 4] = hreg1;
    }
#pragma unroll 1
    for (int s = 0; s < CH; ++s) {
      const int par = s & 1;                  // ch*CH is even -> parity = s&1
      float4 gq = *(const float4*)&G1buf[s * 512 + j * 4];
      // ---- matvec over this thread's k-half (h broadcast from LDS)
      fx2 a0 = {0.f, 0.f}, a1 = {0.f, 0.f}, a2 = {0.f, 0.f}, a3 = {0.f, 0.f};
      fx2 b0 = {0.f, 0.f}, b1 = {0.f, 0.f}, b2 = {0.f, 0.f}, b3 = {0.f, 0.f};
      const float4* h4 = (const float4*)h_sh[par];
#pragma unroll
      for (int q = 0; q < 16; ++q) {
        float4 hv = h4[khalf * 16 + q];
        fx2 e0, e1; e0.x = hv.x; e0.y = hv.y; e1.x = hv.z; e1.y = hv.w;
        a0 += w[0][2 * q] * e0; b0 += w[0][2 * q + 1] * e1;
        a1 += w[1][2 * q] * e0; b1 += w[1][2 * q + 1] * e1;
        a2 += w[2][2 * q] * e0; b2 += w[2][2 * q + 1] * e1;
        a3 += w[3][2 * q] * e0; b3 += w[3][2 * q + 1] * e1;
      }
      float p0 = (a0.x + a0.y) + (b0.x + b0.y);
      float p1 = (a1.x + a1.y) + (b1.x + b1.y);
      float p2 = (a2.x + a2.y) + (b2.x + b2.y);
      float p3 = (a3.x + a3.y) + (b3.x + b3.y);
      p0 = dpp_pair_add(p0);
      p1 = dpp_pair_add(p1);
      p2 = dpp_pair_add(p2);
      p3 = dpp_pair_add(p3);
      // ---- gates (i,f,g,o), replicated in both pair lanes (identical FP ops)
      float iv = p0 + gq.x, fv = p1 + gq.y, gv = p2 + gq.z, ov = p3 + gq.w;
      float si = 1.f / (1.f + __expf(-iv));
      float sf = 1.f / (1.f + __expf(-fv));
      float tg = 1.f - 2.f / (__expf(2.f * gv) + 1.f);
      float so = 1.f / (1.f + __expf(-ov));
      c = sf * c + si * tg;
      float hh = so * (1.f - 2.f / (__expf(2.f * c) + 1.f));
      if (khalf == 0) {
        h_sh[par ^ 1][j] = hh;                // conflict-free (32 consecutive banks/wave)
        hstage[s * NH + j] = hh;
      }
      // ---- LDS-only barrier: global loads/stores stay in flight
      asm volatile("s_waitcnt lgkmcnt(0)\n\ts_barrier" ::: "memory");
    }
    // ---- chunk boundary
    hreg0 = *(const float4*)&hstage[t * 4];         // lane-contiguous: conflict-free
    hreg1 = *(const float4*)&hstage[1024 + t * 4];
    asm volatile("s_waitcnt vmcnt(0)" ::: "memory");  // gpre arrived (issued 16 steps ago)
    if (ch + 1 < NCHUNK) {
#pragma unroll
      for (int i = 0; i < 8; ++i)
        *(float4*)&G1buf[i * 1024 + t * 4] = gpre[i];
    }
    asm volatile("s_waitcnt lgkmcnt(0)\n\ts_barrier" ::: "memory");
  }
  // final chunk's h
  float* dst = hidden + (size_t)(NL - 1 + (NCHUNK - 1) * CH) * NH;
  *(float4*)&dst[t * 4] = hreg0;
  *(float4*)&dst[1024 + t * 4] = hreg1;
  if (t == 0)
    __hip_atomic_store(done, 1, __ATOMIC_RELEASE, __HIP_MEMORY_SCOPE_AGENT);
}

// ------------------------------------------------ one tree level: pair -> parent hidden
__global__ void p2h_kernel(const float* __restrict__ wf, float* __restrict__ hidden, int base) {
  int node = base + blockIdx.x;
  int j = threadIdx.x;                       // 128
  __shared__ __attribute__((aligned(16))) float pr[2 * NH];
  const float* hl = hidden + (size_t)(2 * node + 1) * NH;
  pr[j] = hl[j];
  pr[j + NH] = hl[j + NH];
  __syncthreads();
  float acc = wf[OF_BP2H + j];
  const float4* W4 = (const float4*)(wf + OF_WP2H + (size_t)j * 2 * NH);
  const float4* p4 = (const float4*)pr;
#pragma unroll 16
  for (int q = 0; q < 64; ++q) {
    float4 u = W4[q], x = p4[q];
    acc += u.x * x.x + u.y * x.y + u.z * x.z + u.w * x.w;
  }
  hidden[(size_t)node * NH + j] = acc;
}

// ------------------------------------------------ unary = hidden@W_uni^T + b; zero f2n[0]
__global__ void unary_kernel(const float* __restrict__ wf, const float* __restrict__ hidden,
                             float* __restrict__ unary, float* __restrict__ f2n) {
  int node = blockIdx.x;
  int ct = threadIdx.x;                      // 64
  __shared__ __attribute__((aligned(16))) float hs[NH];
  hs[ct] = hidden[(size_t)node * NH + ct];
  hs[ct + 64] = hidden[(size_t)node * NH + 64 + ct];
  __syncthreads();
  float acc = wf[OF_BUNI + ct];
  const float4* W4 = (const float4*)(wf + OF_WUNI + (size_t)ct * NH);
  const float4* h4 = (const float4*)hs;
#pragma unroll
  for (int q = 0; q < 32; ++q) {
    float4 u = W4[q], x = h4[q];
    acc += u.x * x.x + u.y * x.y + u.z * x.z + u.w * x.w;
  }
  unary[(size_t)node * NT + ct] = acc;
  if (node == 0) f2n[ct] = 0.f;
}

// ------------------------------------------------ edge_fac GEMM: [8192,256]x[256,4096]
__global__ __launch_bounds__(256) void edge_kernel(const float* __restrict__ hidden,
                                                   const float* __restrict__ wf,
                                                   float* __restrict__ edge) {
  __shared__ __attribute__((aligned(16))) float As[32][132];
  __shared__ __attribute__((aligned(16))) float Bs[32][132];
  const int tid = threadIdx.x;
  const int nb = blockIdx.x;                 // 0..31 (N tile of 128)
  const int mb = blockIdx.y;                 // 0..63 (M tile of 128)
  const int tm = tid >> 4, tn = tid & 15;
  float acc[8][8];
#pragma unroll
  for (int i = 0; i < 8; ++i)
#pragma unroll
    for (int j = 0; j < 8; ++j) acc[i][j] = 0.f;
  const int sr = tid >> 1;
  const int sq = tid & 1;
  for (int ch = 0; ch < 8; ++ch) {
    {
      int gm = mb * 128 + sr;
      const float* srcA = (ch < 4) ? hidden + (size_t)(gm >> 1) * NH + ch * 32
                                   : hidden + (size_t)(gm + 1) * NH + (ch - 4) * 32;
      bool ok = (gm < NNODE - 1);
#pragma unroll
      for (int i = 0; i < 4; ++i) {
        int kk = sq * 16 + i * 4;
        float4 v = ok ? *(const float4*)(srcA + kk) : make_float4(0.f, 0.f, 0.f, 0.f);
        As[kk + 0][sr] = v.x; As[kk + 1][sr] = v.y; As[kk + 2][sr] = v.z; As[kk + 3][sr] = v.w;
      }
    }
    {
      int gn = nb * 128 + sr;
      const float* srcB = wf + OF_WEDGE + (size_t)gn * NE + ch * 32;
#pragma unroll
      for (int i = 0; i < 4; ++i) {
        int kk = sq * 16 + i * 4;
        float4 v = *(const float4*)(srcB + kk);
        Bs[kk + 0][sr] = v.x; Bs[kk + 1][sr] = v.y; Bs[kk + 2][sr] = v.z; Bs[kk + 3][sr] = v.w;
      }
    }
    __syncthreads();
#pragma unroll 8
    for (int kk = 0; kk < 32; ++kk) {
      float a[8], b[8];
      *(float4*)(a)     = *(const float4*)&As[kk][tm * 4];
      *(float4*)(a + 4) = *(const float4*)&As[kk][64 + tm * 4];
      *(float4*)(b)     = *(const float4*)&Bs[kk][tn * 4];
      *(float4*)(b + 4) = *(const float4*)&Bs[kk][64 + tn * 4];
#pragma unroll
      for (int i = 0; i < 8; ++i)
#pragma unroll
        for (int j = 0; j < 8; ++j) acc[i][j] += a[i] * b[j];
    }
    __syncthreads();
  }
  float bias[8];
#pragma unroll
  for (int j = 0; j < 8; ++j)
    bias[j] = wf[OF_BEDGE + nb * 128 + (j >> 2) * 64 + tn * 4 + (j & 3)];
#pragma unroll
  for (int i = 0; i < 8; ++i) {
    int gm = mb * 128 + (i >> 2) * 64 + tm * 4 + (i & 3);
    if (gm < NNODE - 1) {
      float* row = edge + (size_t)gm * 4096 + nb * 128;
      float4 o0, o1;
      o0.x = acc[i][0] + bias[0]; o0.y = acc[i][1] + bias[1];
      o0.z = acc[i][2] + bias[2]; o0.w = acc[i][3] + bias[3];
      o1.x = acc[i][4] + bias[4]; o1.y = acc[i][5] + bias[5];
      o1.z = acc[i][6] + bias[6]; o1.w = acc[i][7] + bias[7];
      *(float4*)(row + tn * 4) = o0;
      *(float4*)(row + 64 + tn * 4) = o1;
    }
  }
}

// ------------------------------------------------ upward level (big levels)
__global__ void up_kernel(const float* __restrict__ unary, const float* __restrict__ edge,
                          float* __restrict__ v2f, float* __restrict__ f2p,
                          int base, int depth) {
  int node = base + blockIdx.x;
  int tid = threadIdx.x;                     // 64; tid = p (parent tag)
  __shared__ __attribute__((aligned(16))) float vs[NT];
  float vv = unary[(size_t)node * NT + tid];
  if (depth < NDEPTH)
    vv += f2p[(size_t)(2 * node + 1) * NT + tid] + f2p[(size_t)(2 * node + 2) * NT + tid];
  v2f[(size_t)node * NT + tid] = vv;
  vs[tid] = vv;
  __syncthreads();
  const float4* E4 = (const float4*)(edge + (size_t)(node - 1) * 4096 + tid * 64);
  const float4* v4 = (const float4*)vs;
  float x[NT];
#pragma unroll
  for (int q = 0; q < 16; ++q) {
    float4 e = E4[q], vq = v4[q];
    x[4 * q + 0] = e.x + vq.x; x[4 * q + 1] = e.y + vq.y;
    x[4 * q + 2] = e.z + vq.z; x[4 * q + 3] = e.w + vq.w;
  }
  float m = x[0];
#pragma unroll
  for (int i = 1; i < NT; ++i) m = fmaxf(m, x[i]);
  float s = 0.f;
#pragma unroll
  for (int i = 0; i < NT; ++i) s += __expf(x[i] - m);
  f2p[(size_t)node * NT + tid] = m + __logf(s);
}

// ------------------------------------------------ upward small levels (d=5..0) fused, 1 block
__global__ __launch_bounds__(512) void up_small_kernel(const float* __restrict__ unary,
                                                       const float* __restrict__ edge,
                                                       float* __restrict__ v2f,
                                                       float* __restrict__ f2p) {
  const int g = threadIdx.x >> 6;            // wave/group 0..7
  const int l = threadIdx.x & 63;            // tag
  __shared__ __attribute__((aligned(16))) float vs[8][NT];
  for (int d = 5; d >= 0; --d) {
    const int base = (1 << d) - 1, cnt = 1 << d;
    for (int nn = g; nn < cnt; nn += 8) {
      int node = base + nn;
      float vv = unary[(size_t)node * NT + l] +
                 f2p[(size_t)(2 * node + 1) * NT + l] + f2p[(size_t)(2 * node + 2) * NT + l];
      v2f[(size_t)node * NT + l] = vv;
      vs[g][l] = vv;                         // in-wave visibility
      if (d == 0) break;                     // root: no top edge factor
      const float4* E4 = (const float4*)(edge + (size_t)(node - 1) * 4096 + l * 64);
      const float4* v4 = (const float4*)vs[g];
      float x[NT];
#pragma unroll
      for (int q = 0; q < 16; ++q) {
        float4 e = E4[q], vq = v4[q];
        x[4 * q + 0] = e.x + vq.x; x[4 * q + 1] = e.y + vq.y;
        x[4 * q + 2] = e.z + vq.z; x[4 * q + 3] = e.w + vq.w;
      }
      float m = x[0];
#pragma unroll
      for (int i = 1; i < NT; ++i) m = fmaxf(m, x[i]);
      float s = 0.f;
#pragma unroll
      for (int i = 0; i < NT; ++i) s += __expf(x[i] - m);
      f2p[(size_t)node * NT + l] = m + __logf(s);
    }
    __syncthreads();
  }
}

// ------------------------------------------------ downward level (big levels)
__global__ void down_kernel(const float* __restrict__ unary, const float* __restrict__ edge,
                            const float* __restrict__ f2p, float* __restrict__ f2n,
                            int base) {
  int node = base + blockIdx.x;
  int tid = threadIdx.x;                     // 64; tid = c (child tag)
  int par = (node - 1) >> 1;
  int sib = (node & 1) ? node + 1 : node - 1;
  __shared__ __attribute__((aligned(16))) float us[NT];
  us[tid] = unary[(size_t)par * NT + tid] + f2n[(size_t)par * NT + tid] +
            f2p[(size_t)sib * NT + tid];
  __syncthreads();
  float uu[NT];
  const float4* u4 = (const float4*)us;
#pragma unroll
  for (int q = 0; q < 16; ++q) {
    float4 t4 = u4[q];
    uu[4 * q] = t4.x; uu[4 * q + 1] = t4.y; uu[4 * q + 2] = t4.z; uu[4 * q + 3] = t4.w;
  }
  const float* E = edge + (size_t)(node - 1) * 4096 + tid;
  float x[NT];
#pragma unroll
  for (int p = 0; p < NT; ++p) x[p] = E[(size_t)p * 64] + uu[p];
  float m = x[0];
#pragma unroll
  for (int i = 1; i < NT; ++i) m = fmaxf(m, x[i]);
  float s = 0.f;
#pragma unroll
  for (int i = 0; i < NT; ++i) s += __expf(x[i] - m);
  f2n[(size_t)node * NT + tid] = m + __logf(s);
}

// ------------------------------------------------ downward small levels (d=1..5) fused, 1 block
__global__ __launch_bounds__(512) void down_small_kernel(const float* __restrict__ unary,
                                                         const float* __restrict__ edge,
                                                         const float* __restrict__ f2p,
                                                         float* __restrict__ f2n) {
  const int g = threadIdx.x >> 6;
  const int l = threadIdx.x & 63;
  __shared__ __attribute__((aligned(16))) float us[8][NT];
  for (int d = 1; d <= 5; ++d) {
    const int base = (1 << d) - 1, cnt = 1 << d;
    for (int nn = g; nn < cnt; nn += 8) {
      int node = base + nn;
      int par = (node - 1) >> 1;
      int sib = (node & 1) ? node + 1 : node - 1;
      us[g][l] = unary[(size_t)par * NT + l] + f2n[(size_t)par * NT + l] +
                 f2p[(size_t)sib * NT + l];
      float uu[NT];
      const float4* u4 = (const float4*)us[g];
#pragma unroll
      for (int q = 0; q < 16; ++q) {
        float4 t4 = u4[q];
        uu[4 * q] = t4.x; uu[4 * q + 1] = t4.y; uu[4 * q + 2] = t4.z; uu[4 * q + 3] = t4.w;
      }
      const float* E = edge + (size_t)(node - 1) * 4096 + l;
      float x[NT];
#pragma unroll
      for (int p = 0; p < NT; ++p) x[p] = E[(size_t)p * 64] + uu[p];
      float m = x[0];
#pragma unroll
      for (int i = 1; i < NT; ++i) m = fmaxf(m, x[i]);
      float s = 0.f;
#pragma unroll
      for (int i = 0; i < NT; ++i) s += __expf(x[i] - m);
      f2n[(size_t)node * NT + l] = m + __logf(s);
    }
    __syncthreads();
  }
}

// ------------------------------------------------ beliefs -> postorder -> out (flag dtype)
__global__ void final_kernel(const float* __restrict__ v2f, const float* __restrict__ f2n,
                             const int* __restrict__ flag, void* __restrict__ out) {
  int node = blockIdx.x;
  int tid = threadIdx.x;                     // 64
  unsigned v = (unsigned)node + 1u;
  int d = 31 - __clz((int)v);
  int b0 = 0, S = NNODE;
  for (int b = d - 1; b >= 0; --b) {
    int sz = (S - 1) >> 1;
    if ((v >> b) & 1) b0 += sz;
    S = sz;
  }
  int pos = b0 + S - 1;
  float val = v2f[(size_t)node * NT + tid] + f2n[(size_t)node * NT + tid];
  if ((*flag) > 100) ((float*)out)[(size_t)pos * NT + tid] = val;
  else               ((bf16*)out)[(size_t)pos * NT + tid] = __float2bfloat16(val);
}

// ------------------------------------------------
extern "C" void kernel_launch(void* const* d_in, const int* in_sizes, int n_in,
                              void* d_out, int out_size, void* d_ws, size_t ws_size,
                              hipStream_t stream) {
  (void)in_sizes; (void)n_in; (void)out_size; (void)ws_size;
  const int* tokens = (const int*)d_in[0];

  float* ws     = (float*)d_ws;
  int*   flag   = (int*)ws;                            // [16]; flag[8] = lstm done-flag
  float* wf     = ws + 16;                             // converted f32 weights
  float* hidden = wf + WF_TOTAL;                       // [8191][128]
  float* G1T    = hidden + (size_t)NNODE * NH;         // [4096][512] (transposed gate quads)
  float* unary  = G1T + (size_t)NL * 512;              // [8191][64]
  float* v2f    = unary + (size_t)NNODE * NT;          // [8191][64]
  float* f2p    = v2f + (size_t)NNODE * NT;            // [8191][64]
  float* f2n    = f2p + (size_t)NNODE * NT;            // [8191][64]
  float* edge   = f2n + (size_t)NNODE * NT;            // [8190][4096]

  detect_kernel<<<1, 256, 0, stream>>>(d_in[10], flag);
  convert_kernel<<<(WF_TOTAL + 255) / 256, 256, 0, stream>>>(
      d_in[2], d_in[3], d_in[4], d_in[5], d_in[6], d_in[7],
      d_in[8], d_in[9], d_in[10], d_in[11], flag, wf);
  g1_kernel<<<NL / 8, 512, 0, stream>>>(tokens, d_in[1], flag, wf, G1T);
  lstm_kernel<<<257, 256, 0, stream>>>(wf, G1T, hidden, flag + 8);
  for (int d = NDEPTH - 1; d >= 0; --d)
    p2h_kernel<<<1 << d, 128, 0, stream>>>(wf, hidden, (1 << d) - 1);
  unary_kernel<<<NNODE, 64, 0, stream>>>(wf, hidden, unary, f2n);
  edge_kernel<<<dim3(32, 64), 256, 0, stream>>>(hidden, wf, edge);
  for (int d = NDEPTH; d >= 6; --d)
    up_kernel<<<1 << d, 64, 0, stream>>>(unary, edge, v2f, f2p, (1 << d) - 1, d);
  up_small_kernel<<<1, 512, 0, stream>>>(unary, edge, v2f, f2p);
  down_small_kernel<<<1, 512, 0, stream>>>(unary, edge, f2p, f2n);
  for (int d = 6; d <= NDEPTH; ++d)
    down_kernel<<<1 << d, 64, 0, stream>>>(unary, edge, f2p, f2n, (1 << d) - 1);
  final_kernel<<<NNODE, 64, 0, stream>>>(v2f, f2n, flag, d_out);
}

// Round 7
// 4147.863 us; speedup vs baseline: 1.2974x; 1.2974x over previous
//
#include <hip/hip_runtime.h>
#include <hip/hip_bf16.h>

typedef __hip_bfloat16 bf16;
typedef float fx2 __attribute__((ext_vector_type(2)));

#define NL 4096      // L leaves
#define NH 128       // H hidden
#define NE 256       // E embed
#define NT 64        // T tags
#define NNODE 8191   // N = 2L-1
#define NDEPTH 12    // D = log2(L)
#define CH 16        // LSTM steps per chunk
#define NCHUNK (NL / CH)

// converted f32 weights, offsets into wf[] (floats)
#define OF_WIH   0
#define OF_WHH   131072
#define OF_BIH   196608
#define OF_BHH   197120
#define OF_WP2H  197632
#define OF_BP2H  230400
#define OF_WUNI  230528
#define OF_BUNI  238720
#define OF_WEDGE 238784
#define OF_BEDGE 1287360
#define WF_TOTAL 1291456

__device__ __forceinline__ float b2f(bf16 x) { return __bfloat162float(x); }

// pair-swap (lanes 2k <-> 2k+1) via DPP quad_perm [1,0,3,2] — pure VALU
__device__ __forceinline__ float dpp_pair_add(float x) {
  int yi = __builtin_amdgcn_mov_dpp(__float_as_int(x), 0xB1, 0xF, 0xF, true);
  return x + __int_as_float(yi);
}

// ------------------------------------------------ dtype detection (f32 vs bf16 delivery)
__global__ void detect_kernel(const void* __restrict__ wedge_raw, int* __restrict__ flag) {
  __shared__ int cnt_sh[256];
  const unsigned short* p = (const unsigned short*)wedge_raw;
  int c = 0;
  for (int i = threadIdx.x; i < 32768; i += 256) {
    float v = __uint_as_float(((unsigned)p[2 * i]) << 16);
    if (fabsf(v) > 4.f) c++;
  }
  cnt_sh[threadIdx.x] = c;
  __syncthreads();
  for (int s = 128; s > 0; s >>= 1) {
    if (threadIdx.x < s) cnt_sh[threadIdx.x] += cnt_sh[threadIdx.x + s];
    __syncthreads();
  }
  if (threadIdx.x == 0) flag[0] = cnt_sh[0];   // >100 => inputs are f32
}

// ------------------------------------------------ convert all weights -> f32 in ws
__global__ void convert_kernel(const void* s0, const void* s1, const void* s2, const void* s3,
                               const void* s4, const void* s5, const void* s6, const void* s7,
                               const void* s8, const void* s9,
                               const int* __restrict__ flag, float* __restrict__ wf) {
  int i = blockIdx.x * 256 + threadIdx.x;
  if (i >= WF_TOTAL) return;
  const void* src; int local;
  if      (i < OF_WHH)   { src = s0; local = i; }
  else if (i < OF_BIH)   { src = s1; local = i - OF_WHH; }
  else if (i < OF_BHH)   { src = s2; local = i - OF_BIH; }
  else if (i < OF_WP2H)  { src = s3; local = i - OF_BHH; }
  else if (i < OF_BP2H)  { src = s4; local = i - OF_WP2H; }
  else if (i < OF_WUNI)  { src = s5; local = i - OF_BP2H; }
  else if (i < OF_BUNI)  { src = s6; local = i - OF_WUNI; }
  else if (i < OF_WEDGE) { src = s7; local = i - OF_BUNI; }
  else if (i < OF_BEDGE) { src = s8; local = i - OF_WEDGE; }
  else                   { src = s9; local = i - OF_BEDGE; }
  bool isf32 = (*flag) > 100;
  wf[i] = isf32 ? ((const float*)src)[local] : b2f(((const bf16*)src)[local]);
}

// ------------------------------------------------ G1T = emb[tok]@W_ih^T + b_ih + b_hh
// TRANSPOSED store: G1T[t][j*4 + g] (gates of row j adjacent).
__global__ __launch_bounds__(512) void g1_kernel(const int* __restrict__ tokens,
                                                 const void* __restrict__ emb_raw,
                                                 const int* __restrict__ flag,
                                                 const float* __restrict__ wf,
                                                 float* __restrict__ G1T) {
  __shared__ __attribute__((aligned(16))) float xs[8 * NE];
  const bool isf32 = (*flag) > 100;
  const int t0 = blockIdx.x * 8;
  for (int q = threadIdx.x; q < 8 * NE; q += 512) {
    int tok = q >> 8, e = q & 255;
    size_t off = (size_t)tokens[t0 + tok] * NE + e;
    xs[q] = isf32 ? ((const float*)emb_raw)[off] : b2f(((const bf16*)emb_raw)[off]);
  }
  __syncthreads();
  const int r = threadIdx.x;
  const float bias = wf[OF_BIH + r] + wf[OF_BHH + r];
  float acc[8];
#pragma unroll
  for (int k = 0; k < 8; ++k) acc[k] = bias;
  const float4* W4 = (const float4*)(wf + OF_WIH + (size_t)r * NE);
#pragma unroll 8
  for (int j = 0; j < 64; ++j) {
    float4 wv = W4[j];
#pragma unroll
    for (int tok = 0; tok < 8; ++tok) {
      float4 xv = ((const float4*)(xs + tok * NE))[j];
      acc[tok] += wv.x * xv.x + wv.y * xv.y + wv.z * xv.z + wv.w * xv.w;
    }
  }
  const int jj = r & 127, gg = r >> 7;
#pragma unroll
  for (int tok = 0; tok < 8; ++tok)
    G1T[(size_t)(t0 + tok) * 512 + jj * 4 + gg] = acc[tok];
}

// ------------------------------------------------ sequential LSTM, 1 block, 512 threads
// Thread (r = t>>1, khalf = t&1) holds W_hh rows {r, r+256} restricted to its
// 64-wide k-half: 128 f32 in *architectural* VGPRs (launch_bounds 512,2 => 256
// VGPR budget, W + ds_read landing slots fit -> fully pipelined LDS reads), and
// 8 waves = 2 waves/SIMD for latency hiding. Pair lanes combine k-halves via
// DPP; per-row sums land in gq_sh[4j+gate] so the gate phase (threads<128) does
// 2 b128 reads. Two LDS-only barriers/step; zero global ops in the step body
// (G1 chunk prefetch + h flush per 16-step chunk, 16 steps of vmcnt slack).
__global__ __launch_bounds__(512, 2) void lstm_kernel(const float* __restrict__ wf,
                                                      const float* __restrict__ G1T,
                                                      float* __restrict__ hidden) {
  const int t = threadIdx.x;
  const int r = t >> 1;                       // 0..255 -> rows {r, r+256}
  const int khalf = t & 1;
  __shared__ __attribute__((aligned(16))) float h_sh[2][NH];        // 1 KB ping-pong
  __shared__ __attribute__((aligned(16))) float gq_sh[512];         // 2 KB gate sums
  __shared__ __attribute__((aligned(16))) float G1buf[CH * 512];    // 32 KB gate chunk
  __shared__ __attribute__((aligned(16))) float hstage[CH * NH];    // 8 KB leaf-h stage
  fx2 w0[32], w1[32];                         // 2 rows x 64 f32 (this k-half)
  {
    const float4* Wr0 = (const float4*)(wf + OF_WHH + (size_t)r * NH + khalf * 64);
    const float4* Wr1 = (const float4*)(wf + OF_WHH + (size_t)(r + 256) * NH + khalf * 64);
#pragma unroll
    for (int q = 0; q < 16; ++q) {
      float4 v0 = Wr0[q], v1 = Wr1[q];
      fx2 a, b;
      a.x = v0.x; a.y = v0.y; b.x = v0.z; b.y = v0.w;
      w0[2 * q] = a; w0[2 * q + 1] = b;
      a.x = v1.x; a.y = v1.y; b.x = v1.z; b.y = v1.w;
      w1[2 * q] = a; w1[2 * q + 1] = b;
    }
  }
  // gq_sh destination indices: row r -> gate (r>>7), j = r&127; row r+256 -> gate+2
  const int idx0 = 4 * (r & 127) + (r >> 7);
  const int idx1 = idx0 + 2;
  float c = 0.f;
  float4 hreg;                                // boundary h flush register
  if (t < NH) h_sh[0][t] = 0.f;
  {                                           // preload chunk 0 straight into LDS
#pragma unroll
    for (int i = 0; i < 4; ++i) {
      float4 v = *(const float4*)&G1T[(size_t)i * 2048 + t * 4];
      *(float4*)&G1buf[i * 2048 + t * 4] = v;   // lane-contiguous: conflict-free
    }
  }
  __syncthreads();                            // full drain once, pre-loop
  for (int ch = 0; ch < NCHUNK; ++ch) {
    // ---- issue next chunk's G1 loads + previous chunk's h store (16 steps of slack)
    float4 gpre[4];
    {
      const float* gsrc = G1T + (size_t)((ch + 1 < NCHUNK) ? ch + 1 : NCHUNK - 1) * (CH * 512);
#pragma unroll
      for (int i = 0; i < 4; ++i)
        gpre[i] = *(const float4*)&gsrc[i * 2048 + t * 4];
    }
    if (ch > 0)
      *(float4*)&hidden[(size_t)(NL - 1 + (ch - 1) * CH) * NH + t * 4] = hreg;
#pragma unroll 1
    for (int s = 0; s < CH; ++s) {
      const int par = s & 1;
      // ---- matvec over this thread's k-half, 2 rows (h broadcast from LDS)
      fx2 a0 = {0.f, 0.f}, a1 = {0.f, 0.f}, b0 = {0.f, 0.f}, b1 = {0.f, 0.f};
      const float4* h4 = (const float4*)h_sh[par] + khalf * 16;
#pragma unroll
      for (int q = 0; q < 16; ++q) {
        float4 hv = h4[q];
        fx2 e0, e1; e0.x = hv.x; e0.y = hv.y; e1.x = hv.z; e1.y = hv.w;
        a0 += w0[2 * q] * e0; a1 += w0[2 * q + 1] * e1;
        b0 += w1[2 * q] * e0; b1 += w1[2 * q + 1] * e1;
      }
      float s0 = (a0.x + a0.y) + (a1.x + a1.y);
      float s1 = (b0.x + b0.y) + (b1.x + b1.y);
      s0 = dpp_pair_add(s0);                  // pair lanes now both hold full row sums
      s1 = dpp_pair_add(s1);
      if (khalf == 0) { gq_sh[idx0] = s0; gq_sh[idx1] = s1; }
      asm volatile("s_waitcnt lgkmcnt(0)\n\ts_barrier" ::: "memory");
      // ---- gate phase: threads 0..127, j = t
      if (t < NH) {
        float4 pq = *(const float4*)&gq_sh[4 * t];            // (i,f,g,o) W_hh sums
        float4 gq = *(const float4*)&G1buf[s * 512 + 4 * t];  // W_ih x + biases
        float iv = pq.x + gq.x, fv = pq.y + gq.y, gv = pq.z + gq.z, ov = pq.w + gq.w;
        float si = 1.f / (1.f + __expf(-iv));
        float sf = 1.f / (1.f + __expf(-fv));
        float tg = 1.f - 2.f / (__expf(2.f * gv) + 1.f);
        float so = 1.f / (1.f + __expf(-ov));
        c = sf * c + si * tg;
        float hh = so * (1.f - 2.f / (__expf(2.f * c) + 1.f));
        h_sh[par ^ 1][t] = hh;                // ping-pong: no WAR with this step's reads
        hstage[s * NH + t] = hh;              // conflict-free (contiguous)
      }
      asm volatile("s_waitcnt lgkmcnt(0)\n\ts_barrier" ::: "memory");
    }
    // ---- chunk boundary
    hreg = *(const float4*)&hstage[t * 4];          // lane-contiguous: conflict-free
    asm volatile("s_waitcnt vmcnt(0)" ::: "memory");  // gpre arrived (16 steps old)
    if (ch + 1 < NCHUNK) {
#pragma unroll
      for (int i = 0; i < 4; ++i)
        *(float4*)&G1buf[i * 2048 + t * 4] = gpre[i];
    }
    asm volatile("s_waitcnt lgkmcnt(0)\n\ts_barrier" ::: "memory");
  }
  // final chunk's h
  *(float4*)&hidden[(size_t)(NL - 1 + (NCHUNK - 1) * CH) * NH + t * 4] = hreg;
}

// ------------------------------------------------ one tree level: pair -> parent hidden
__global__ void p2h_kernel(const float* __restrict__ wf, float* __restrict__ hidden, int base) {
  int node = base + blockIdx.x;
  int j = threadIdx.x;                       // 128
  __shared__ __attribute__((aligned(16))) float pr[2 * NH];
  const float* hl = hidden + (size_t)(2 * node + 1) * NH;
  pr[j] = hl[j];
  pr[j + NH] = hl[j + NH];
  __syncthreads();
  float acc = wf[OF_BP2H + j];
  const float4* W4 = (const float4*)(wf + OF_WP2H + (size_t)j * 2 * NH);
  const float4* p4 = (const float4*)pr;
#pragma unroll 16
  for (int q = 0; q < 64; ++q) {
    float4 u = W4[q], x = p4[q];
    acc += u.x * x.x + u.y * x.y + u.z * x.z + u.w * x.w;
  }
  hidden[(size_t)node * NH + j] = acc;
}

// ------------------------------------------------ unary = hidden@W_uni^T + b; zero f2n[0]
__global__ void unary_kernel(const float* __restrict__ wf, const float* __restrict__ hidden,
                             float* __restrict__ unary, float* __restrict__ f2n) {
  int node = blockIdx.x;
  int ct = threadIdx.x;                      // 64
  __shared__ __attribute__((aligned(16))) float hs[NH];
  hs[ct] = hidden[(size_t)node * NH + ct];
  hs[ct + 64] = hidden[(size_t)node * NH + 64 + ct];
  __syncthreads();
  float acc = wf[OF_BUNI + ct];
  const float4* W4 = (const float4*)(wf + OF_WUNI + (size_t)ct * NH);
  const float4* h4 = (const float4*)hs;
#pragma unroll
  for (int q = 0; q < 32; ++q) {
    float4 u = W4[q], x = h4[q];
    acc += u.x * x.x + u.y * x.y + u.z * x.z + u.w * x.w;
  }
  unary[(size_t)node * NT + ct] = acc;
  if (node == 0) f2n[ct] = 0.f;
}

// ------------------------------------------------ edge_fac GEMM: [8192,256]x[256,4096]
__global__ __launch_bounds__(256) void edge_kernel(const float* __restrict__ hidden,
                                                   const float* __restrict__ wf,
                                                   float* __restrict__ edge) {
  __shared__ __attribute__((aligned(16))) float As[32][132];
  __shared__ __attribute__((aligned(16))) float Bs[32][132];
  const int tid = threadIdx.x;
  const int nb = blockIdx.x;                 // 0..31 (N tile of 128)
  const int mb = blockIdx.y;                 // 0..63 (M tile of 128)
  const int tm = tid >> 4, tn = tid & 15;
  float acc[8][8];
#pragma unroll
  for (int i = 0; i < 8; ++i)
#pragma unroll
    for (int j = 0; j < 8; ++j) acc[i][j] = 0.f;
  const int sr = tid >> 1;
  const int sq = tid & 1;
  for (int ch = 0; ch < 8; ++ch) {
    {
      int gm = mb * 128 + sr;
      const float* srcA = (ch < 4) ? hidden + (size_t)(gm >> 1) * NH + ch * 32
                                   : hidden + (size_t)(gm + 1) * NH + (ch - 4) * 32;
      bool ok = (gm < NNODE - 1);
#pragma unroll
      for (int i = 0; i < 4; ++i) {
        int kk = sq * 16 + i * 4;
        float4 v = ok ? *(const float4*)(srcA + kk) : make_float4(0.f, 0.f, 0.f, 0.f);
        As[kk + 0][sr] = v.x; As[kk + 1][sr] = v.y; As[kk + 2][sr] = v.z; As[kk + 3][sr] = v.w;
      }
    }
    {
      int gn = nb * 128 + sr;
      const float* srcB = wf + OF_WEDGE + (size_t)gn * NE + ch * 32;
#pragma unroll
      for (int i = 0; i < 4; ++i) {
        int kk = sq * 16 + i * 4;
        float4 v = *(const float4*)(srcB + kk);
        Bs[kk + 0][sr] = v.x; Bs[kk + 1][sr] = v.y; Bs[kk + 2][sr] = v.z; Bs[kk + 3][sr] = v.w;
      }
    }
    __syncthreads();
#pragma unroll 8
    for (int kk = 0; kk < 32; ++kk) {
      float a[8], b[8];
      *(float4*)(a)     = *(const float4*)&As[kk][tm * 4];
      *(float4*)(a + 4) = *(const float4*)&As[kk][64 + tm * 4];
      *(float4*)(b)     = *(const float4*)&Bs[kk][tn * 4];
      *(float4*)(b + 4) = *(const float4*)&Bs[kk][64 + tn * 4];
#pragma unroll
      for (int i = 0; i < 8; ++i)
#pragma unroll
        for (int j = 0; j < 8; ++j) acc[i][j] += a[i] * b[j];
    }
    __syncthreads();
  }
  float bias[8];
#pragma unroll
  for (int j = 0; j < 8; ++j)
    bias[j] = wf[OF_BEDGE + nb * 128 + (j >> 2) * 64 + tn * 4 + (j & 3)];
#pragma unroll
  for (int i = 0; i < 8; ++i) {
    int gm = mb * 128 + (i >> 2) * 64 + tm * 4 + (i & 3);
    if (gm < NNODE - 1) {
      float* row = edge + (size_t)gm * 4096 + nb * 128;
      float4 o0, o1;
      o0.x = acc[i][0] + bias[0]; o0.y = acc[i][1] + bias[1];
      o0.z = acc[i][2] + bias[2]; o0.w = acc[i][3] + bias[3];
      o1.x = acc[i][4] + bias[4]; o1.y = acc[i][5] + bias[5];
      o1.z = acc[i][6] + bias[6]; o1.w = acc[i][7] + bias[7];
      *(float4*)(row + tn * 4) = o0;
      *(float4*)(row + 64 + tn * 4) = o1;
    }
  }
}

// ------------------------------------------------ upward level (big levels)
__global__ void up_kernel(const float* __restrict__ unary, const float* __restrict__ edge,
                          float* __restrict__ v2f, float* __restrict__ f2p,
                          int base, int depth) {
  int node = base + blockIdx.x;
  int tid = threadIdx.x;                     // 64; tid = p (parent tag)
  __shared__ __attribute__((aligned(16))) float vs[NT];
  float vv = unary[(size_t)node * NT + tid];
  if (depth < NDEPTH)
    vv += f2p[(size_t)(2 * node + 1) * NT + tid] + f2p[(size_t)(2 * node + 2) * NT + tid];
  v2f[(size_t)node * NT + tid] = vv;
  vs[tid] = vv;
  __syncthreads();
  const float4* E4 = (const float4*)(edge + (size_t)(node - 1) * 4096 + tid * 64);
  const float4* v4 = (const float4*)vs;
  float x[NT];
#pragma unroll
  for (int q = 0; q < 16; ++q) {
    float4 e = E4[q], vq = v4[q];
    x[4 * q + 0] = e.x + vq.x; x[4 * q + 1] = e.y + vq.y;
    x[4 * q + 2] = e.z + vq.z; x[4 * q + 3] = e.w + vq.w;
  }
  float m = x[0];
#pragma unroll
  for (int i = 1; i < NT; ++i) m = fmaxf(m, x[i]);
  float s = 0.f;
#pragma unroll
  for (int i = 0; i < NT; ++i) s += __expf(x[i] - m);
  f2p[(size_t)node * NT + tid] = m + __logf(s);
}

// ------------------------------------------------ upward small levels (d=5..0) fused, 1 block
__global__ __launch_bounds__(512) void up_small_kernel(const float* __restrict__ unary,
                                                       const float* __restrict__ edge,
                                                       float* __restrict__ v2f,
                                                       float* __restrict__ f2p) {
  const int g = threadIdx.x >> 6;            // wave/group 0..7
  const int l = threadIdx.x & 63;            // tag
  __shared__ __attribute__((aligned(16))) float vs[8][NT];
  for (int d = 5; d >= 0; --d) {
    const int base = (1 << d) - 1, cnt = 1 << d;
    for (int nn = g; nn < cnt; nn += 8) {
      int node = base + nn;
      float vv = unary[(size_t)node * NT + l] +
                 f2p[(size_t)(2 * node + 1) * NT + l] + f2p[(size_t)(2 * node + 2) * NT + l];
      v2f[(size_t)node * NT + l] = vv;
      vs[g][l] = vv;                         // in-wave visibility
      if (d == 0) break;                     // root: no top edge factor
      const float4* E4 = (const float4*)(edge + (size_t)(node - 1) * 4096 + l * 64);
      const float4* v4 = (const float4*)vs[g];
      float x[NT];
#pragma unroll
      for (int q = 0; q < 16; ++q) {
        float4 e = E4[q], vq = v4[q];
        x[4 * q + 0] = e.x + vq.x; x[4 * q + 1] = e.y + vq.y;
        x[4 * q + 2] = e.z + vq.z; x[4 * q + 3] = e.w + vq.w;
      }
      float m = x[0];
#pragma unroll
      for (int i = 1; i < NT; ++i) m = fmaxf(m, x[i]);
      float s = 0.f;
#pragma unroll
      for (int i = 0; i < NT; ++i) s += __expf(x[i] - m);
      f2p[(size_t)node * NT + l] = m + __logf(s);
    }
    __syncthreads();
  }
}

// ------------------------------------------------ downward level (big levels)
__global__ void down_kernel(const float* __restrict__ unary, const float* __restrict__ edge,
                            const float* __restrict__ f2p, float* __restrict__ f2n,
                            int base) {
  int node = base + blockIdx.x;
  int tid = threadIdx.x;                     // 64; tid = c (child tag)
  int par = (node - 1) >> 1;
  int sib = (node & 1) ? node + 1 : node - 1;
  __shared__ __attribute__((aligned(16))) float us[NT];
  us[tid] = unary[(size_t)par * NT + tid] + f2n[(size_t)par * NT + tid] +
            f2p[(size_t)sib * NT + tid];
  __syncthreads();
  float uu[NT];
  const float4* u4 = (const float4*)us;
#pragma unroll
  for (int q = 0; q < 16; ++q) {
    float4 t4 = u4[q];
    uu[4 * q] = t4.x; uu[4 * q + 1] = t4.y; uu[4 * q + 2] = t4.z; uu[4 * q + 3] = t4.w;
  }
  const float* E = edge + (size_t)(node - 1) * 4096 + tid;
  float x[NT];
#pragma unroll
  for (int p = 0; p < NT; ++p) x[p] = E[(size_t)p * 64] + uu[p];
  float m = x[0];
#pragma unroll
  for (int i = 1; i < NT; ++i) m = fmaxf(m, x[i]);
  float s = 0.f;
#pragma unroll
  for (int i = 0; i < NT; ++i) s += __expf(x[i] - m);
  f2n[(size_t)node * NT + tid] = m + __logf(s);
}

// ------------------------------------------------ downward small levels (d=1..5) fused, 1 block
__global__ __launch_bounds__(512) void down_small_kernel(const float* __restrict__ unary,
                                                         const float* __restrict__ edge,
                                                         const float* __restrict__ f2p,
                                                         float* __restrict__ f2n) {
  const int g = threadIdx.x >> 6;
  const int l = threadIdx.x & 63;
  __shared__ __attribute__((aligned(16))) float us[8][NT];
  for (int d = 1; d <= 5; ++d) {
    const int base = (1 << d) - 1, cnt = 1 << d;
    for (int nn = g; nn < cnt; nn += 8) {
      int node = base + nn;
      int par = (node - 1) >> 1;
      int sib = (node & 1) ? node + 1 : node - 1;
      us[g][l] = unary[(size_t)par * NT + l] + f2n[(size_t)par * NT + l] +
                 f2p[(size_t)sib * NT + l];
      float uu[NT];
      const float4* u4 = (const float4*)us[g];
#pragma unroll
      for (int q = 0; q < 16; ++q) {
        float4 t4 = u4[q];
        uu[4 * q] = t4.x; uu[4 * q + 1] = t4.y; uu[4 * q + 2] = t4.z; uu[4 * q + 3] = t4.w;
      }
      const float* E = edge + (size_t)(node - 1) * 4096 + l;
      float x[NT];
#pragma unroll
      for (int p = 0; p < NT; ++p) x[p] = E[(size_t)p * 64] + uu[p];
      float m = x[0];
#pragma unroll
      for (int i = 1; i < NT; ++i) m = fmaxf(m, x[i]);
      float s = 0.f;
#pragma unroll
      for (int i = 0; i < NT; ++i) s += __expf(x[i] - m);
      f2n[(size_t)node * NT + l] = m + __logf(s);
    }
    __syncthreads();
  }
}

// ------------------------------------------------ beliefs -> postorder -> out (flag dtype)
__global__ void final_kernel(const float* __restrict__ v2f, const float* __restrict__ f2n,
                             const int* __restrict__ flag, void* __restrict__ out) {
  int node = blockIdx.x;
  int tid = threadIdx.x;                     // 64
  unsigned v = (unsigned)node + 1u;
  int d = 31 - __clz((int)v);
  int b0 = 0, S = NNODE;
  for (int b = d - 1; b >= 0; --b) {
    int sz = (S - 1) >> 1;
    if ((v >> b) & 1) b0 += sz;
    S = sz;
  }
  int pos = b0 + S - 1;
  float val = v2f[(size_t)node * NT + tid] + f2n[(size_t)node * NT + tid];
  if ((*flag) > 100) ((float*)out)[(size_t)pos * NT + tid] = val;
  else               ((bf16*)out)[(size_t)pos * NT + tid] = __float2bfloat16(val);
}

// ------------------------------------------------
extern "C" void kernel_launch(void* const* d_in, const int* in_sizes, int n_in,
                              void* d_out, int out_size, void* d_ws, size_t ws_size,
                              hipStream_t stream) {
  (void)in_sizes; (void)n_in; (void)out_size; (void)ws_size;
  const int* tokens = (const int*)d_in[0];

  float* ws     = (float*)d_ws;
  int*   flag   = (int*)ws;                            // [16]
  float* wf     = ws + 16;                             // converted f32 weights
  float* hidden = wf + WF_TOTAL;                       // [8191][128]
  float* G1T    = hidden + (size_t)NNODE * NH;         // [4096][512] (transposed gate quads)
  float* unary  = G1T + (size_t)NL * 512;              // [8191][64]
  float* v2f    = unary + (size_t)NNODE * NT;          // [8191][64]
  float* f2p    = v2f + (size_t)NNODE * NT;            // [8191][64]
  float* f2n    = f2p + (size_t)NNODE * NT;            // [8191][64]
  float* edge   = f2n + (size_t)NNODE * NT;            // [8190][4096]

  detect_kernel<<<1, 256, 0, stream>>>(d_in[10], flag);
  convert_kernel<<<(WF_TOTAL + 255) / 256, 256, 0, stream>>>(
      d_in[2], d_in[3], d_in[4], d_in[5], d_in[6], d_in[7],
      d_in[8], d_in[9], d_in[10], d_in[11], flag, wf);
  g1_kernel<<<NL / 8, 512, 0, stream>>>(tokens, d_in[1], flag, wf, G1T);
  lstm_kernel<<<1, 512, 0, stream>>>(wf, G1T, hidden);
  for (int d = NDEPTH - 1; d >= 0; --d)
    p2h_kernel<<<1 << d, 128, 0, stream>>>(wf, hidden, (1 << d) - 1);
  unary_kernel<<<NNODE, 64, 0, stream>>>(wf, hidden, unary, f2n);
  edge_kernel<<<dim3(32, 64), 256, 0, stream>>>(hidden, wf, edge);
  for (int d = NDEPTH; d >= 6; --d)
    up_kernel<<<1 << d, 64, 0, stream>>>(unary, edge, v2f, f2p, (1 << d) - 1, d);
  up_small_kernel<<<1, 512, 0, stream>>>(unary, edge, v2f, f2p);
  down_small_kernel<<<1, 512, 0, stream>>>(unary, edge, f2p, f2n);
  for (int d = 6; d <= NDEPTH; ++d)
    down_kernel<<<1 << d, 64, 0, stream>>>(unary, edge, f2p, f2n, (1 << d) - 1);
  final_kernel<<<NNODE, 64, 0, stream>>>(v2f, f2n, flag, d_out);
}